// Round 14
// baseline (147.147 us; speedup 1.0000x reference)
//
#include <hip/hip_runtime.h>
#include <hip/hip_bf16.h>

#define IN_DIM 512
#define OUT_DIM 512

typedef unsigned short u16;
typedef __attribute__((ext_vector_type(4))) float f32x4;
typedef __attribute__((ext_vector_type(8))) __bf16 bf16x8;

// Direct global->LDS DMA, 16B per lane. LDS dest is wave-uniform base + lane*16.
#define GLD16(gp, lp) __builtin_amdgcn_global_load_lds(                       \
    (const __attribute__((address_space(1))) void*)(gp),                      \
    (__attribute__((address_space(3))) void*)(lp), 16, 0, 0)

__device__ __forceinline__ float softplus_f(float r) {
    return (r > 15.0f) ? r : log1pf(expf(r));
}

// ---------------------------------------------------------------------------
// Kernel 1: fold w = w_mu + softplus(w_rho)*w_eps -> bf16 [OUT][IN] (K-major),
//           b = b_mu + softplus(b_rho)*b_eps -> f32 [OUT], into workspace.
// ---------------------------------------------------------------------------
__global__ void prep_kernel(const float* __restrict__ wmu, const float* __restrict__ wrho,
                            const float* __restrict__ weps, const float* __restrict__ bmu,
                            const float* __restrict__ brho, const float* __restrict__ beps,
                            u16* __restrict__ wbf, float* __restrict__ bias) {
    int gid = blockIdx.x * 256 + threadIdx.x;
    int i4 = gid * 4;
    const float4 mu  = *(const float4*)(wmu + i4);
    const float4 rho = *(const float4*)(wrho + i4);
    const float4 ep  = *(const float4*)(weps + i4);
    union { __bf16 h[4]; uint2 u; } pk;
    pk.h[0] = (__bf16)(mu.x + softplus_f(rho.x) * ep.x);
    pk.h[1] = (__bf16)(mu.y + softplus_f(rho.y) * ep.y);
    pk.h[2] = (__bf16)(mu.z + softplus_f(rho.z) * ep.z);
    pk.h[3] = (__bf16)(mu.w + softplus_f(rho.w) * ep.w);
    *(uint2*)(wbf + i4) = pk.u;
    if (gid < OUT_DIM) {
        bias[gid] = bmu[gid] + softplus_f(brho[gid]) * beps[gid];
    }
}

// ---------------------------------------------------------------------------
// Kernel 1b: x (f32) -> x_bf16, streaming (BW-bound, ~30 us).
// ---------------------------------------------------------------------------
__global__ void cvt_kernel(const float* __restrict__ x, u16* __restrict__ xb) {
    const size_t base = (size_t)blockIdx.x * 8192 + threadIdx.x * 4;
#pragma unroll
    for (int i = 0; i < 8; ++i) {
        const float4 a = *(const float4*)(x + base + (size_t)i * 1024);
        union { __bf16 h[4]; uint2 u; } pk;
        pk.h[0] = (__bf16)a.x; pk.h[1] = (__bf16)a.y;
        pk.h[2] = (__bf16)a.z; pk.h[3] = (__bf16)a.w;
        *(uint2*)(xb + base + (size_t)i * 1024) = pk.u;
    }
}

// ---------------------------------------------------------------------------
// Kernel 2: y = x @ w^T + b, fused dropout.  FAT-STEP 2-phase pipeline.
//
// Insight (R13 + m230 cross-check): the vmcnt(0)+barrier step has a quasi-
// fixed ~6.6k-cycle cost (staging-latency dominated). Throughput = #steps,
// not work/step. So: quarter the step count, fatten each step.
//
// Block 256M x 256N, 1024 thr = 16 waves (4M x 4N), wave 64x64, BK=64,
// 8 K-steps. LDS = 2buf x (A 32KB + B 32KB) = 128 KB -> 1 block/CU,
// 16 waves/CU (same as R13, now in one block). Grid 512 = 2 generations.
// Each K-half (32 u16) uses the R13-proven [256][32] source-permuted layout:
//   stored chunk p holds global chunk g = p ^ (row&3) ^ ((row>>2)&3)
//   read chunk ap = lk ^ (l15&3) ^ ((l15>>2)&3)   (2-way max, measured OK)
// Per step: stage 64 KB (4 GLD16/thr) -> 16 ds_read_b128 + 32 MFMA per wave
// (~3.6k cy content) -> staging latency fully hidden -> drain amortized.
// ---------------------------------------------------------------------------
__global__ __launch_bounds__(1024, 4) void bayes_gemm_kernel(
    const u16* __restrict__ xb, const float* __restrict__ du,
    const u16* __restrict__ wbf, const float* __restrict__ bias,
    float* __restrict__ out)
{
    __shared__ u16 lA[2][2][256 * 32];   // [buf][k-half][row][chunk] : 64 KB
    __shared__ u16 lB[2][2][256 * 32];   // 64 KB

    const int raw   = blockIdx.x;
    const int lid   = (raw & 7) * 64 + (raw >> 3);   // 512 % 8 == 0 -> bijective
    const int mband = lid >> 1;      // 0..255 : 256-row band
    const int nband = lid & 1;       // 0..1   : 256-col band (2 sibs same XCD)

    const int tid  = threadIdx.x;
    const int lane = tid & 63;
    const int wv   = tid >> 6;       // 0..15
    const int wm   = wv >> 2;        // 0..3
    const int wn   = wv & 3;         // 0..3
    const int l15  = lane & 15;
    const int lk   = lane >> 4;      // 0..3

    const int row0 = mband * 256;
    const int colb = nband * 256;

    // ---- staging geometry: 1024 thr cover one [256][32] half per GLD16.
    // thread t -> row t>>2, chunk p = t&3; source g = p ^ (row&3) ^ ((row>>2)&3)
    //           = (t&3) ^ ((t>>2)&3) ^ ((t>>4)&3).
    const int sg  = ((tid & 3) ^ ((tid >> 2) & 3) ^ ((tid >> 4) & 3)) * 8;  // u16
    const int trc = tid >> 2;                        // 0..255
    const u16* gA = xb  + (size_t)(row0 + trc) * IN_DIM + sg;
    const u16* gB = wbf + (size_t)(colb + trc) * IN_DIM + sg;
    const int lso = trc * 32 + (tid & 3) * 8;        // u16 idx within a half

    // fragment-read chunk permutation (row&3 = l15&3 since bases are mult of 16)
    const int ap = (lk ^ (l15 & 3) ^ ((l15 >> 2) & 3)) * 8;

    f32x4 acc[4][4] = {};   // [m][n]

    auto stage = [&](int t, int buf) {
        GLD16(gA + t * 64,      &lA[buf][0][lso]);   // A k-half 0
        GLD16(gA + t * 64 + 32, &lA[buf][1][lso]);   // A k-half 1
        GLD16(gB + t * 64,      &lB[buf][0][lso]);   // B k-half 0
        GLD16(gB + t * 64 + 32, &lB[buf][1][lso]);   // B k-half 1
    };

    // ---- prologue
    stage(0, 0);
    __syncthreads();

#pragma unroll
    for (int t = 0; t < 8; ++t) {
        const int buf = t & 1;
        if (t + 1 < 8) stage(t + 1, buf ^ 1);   // async DMA, hidden under fat step

#pragma unroll
        for (int kk = 0; kk < 2; ++kk) {
            bf16x8 bfr[4], afr[4];
#pragma unroll
            for (int n = 0; n < 4; ++n) {
                int c = wn * 64 + n * 16 + l15;
                bfr[n] = *(const bf16x8*)&lB[buf][kk][c * 32 + ap];
            }
#pragma unroll
            for (int m = 0; m < 4; ++m) {
                int r = wm * 64 + m * 16 + l15;
                afr[m] = *(const bf16x8*)&lA[buf][kk][r * 32 + ap];
            }
#pragma unroll
            for (int m = 0; m < 4; ++m)
#pragma unroll
                for (int n = 0; n < 4; ++n)
                    acc[m][n] = __builtin_amdgcn_mfma_f32_16x16x32_bf16(
                        bfr[n], afr[m], acc[m][n], 0, 0, 0);
        }

        __syncthreads();
    }

    // ---- epilogue: bias + inverted dropout, dwordx4 throughout
#pragma unroll
    for (int m = 0; m < 4; ++m) {
#pragma unroll
        for (int n = 0; n < 4; ++n) {
            const int colB = colb + wn * 64 + n * 16 + lk * 4;
            const float4 b4 = *(const float4*)(bias + colB);
            size_t off = (size_t)(row0 + wm * 64 + m * 16 + l15) * OUT_DIM + colB;
            const float4 u4 = *(const float4*)(du + off);
            float4 o;
            o.x = (acc[m][n][0] + b4.x) * ((u4.x >= 0.2f) ? 1.25f : 0.0f);
            o.y = (acc[m][n][1] + b4.y) * ((u4.y >= 0.2f) ? 1.25f : 0.0f);
            o.z = (acc[m][n][2] + b4.z) * ((u4.z >= 0.2f) ? 1.25f : 0.0f);
            o.w = (acc[m][n][3] + b4.w) * ((u4.w >= 0.2f) ? 1.25f : 0.0f);
            *(float4*)(out + off) = o;
        }
    }
}

// ---------------------------------------------------------------------------
// Fallback (ws too small for x_bf16): R5-style f32-A staged kernel.
// ---------------------------------------------------------------------------
__global__ __launch_bounds__(256, 3) void bayes_gemm_f32a(
    const float* __restrict__ x, const float* __restrict__ du,
    const u16* __restrict__ wbf, const float* __restrict__ bias,
    float* __restrict__ out)
{
    __shared__ float lAf[2][128 * 32];
    __shared__ u16   lBf[2][128 * 32];

    const int raw   = blockIdx.x;
    const int lid   = (raw & 7) * 256 + (raw >> 3);
    const int mband = lid >> 2;
    const int nband = lid & 3;

    const int tid  = threadIdx.x;
    const int lane = tid & 63;
    const int wv   = tid >> 6;
    const int wm   = wv >> 1;
    const int wn   = wv & 1;
    const int l15  = lane & 15;
    const int lk   = lane >> 4;

    const int row0 = mband * 128;
    const int colb = nband * 128;

    const int arow  = wv * 8 + (lane >> 3);
    const int acswz = ((lane & 7) ^ (lane >> 3)) * 4;
    const float* gA = x + (size_t)(row0 + arow) * IN_DIM + acswz;
    const int brow  = wv * 16 + (lane >> 2);
    const int bcswz = ((lane & 3) ^ ((lane >> 3) & 3)) * 8;
    const u16* gB = wbf + (size_t)(colb + brow) * IN_DIM + bcswz;

    f32x4 acc[4][4] = {};

    auto stage = [&](int t, int buf) {
#pragma unroll
        for (int i = 0; i < 4; ++i)
            GLD16(gA + (size_t)i * 32 * IN_DIM + t * 32, &lAf[buf][i * 1024 + wv * 256]);
#pragma unroll
        for (int i = 0; i < 2; ++i)
            GLD16(gB + (size_t)i * 64 * IN_DIM + t * 32, &lBf[buf][i * 2048 + wv * 512]);
    };

    stage(0, 0);
    __syncthreads();

#pragma unroll
    for (int t = 0; t < 16; ++t) {
        const int buf = t & 1;
        if (t + 1 < 16) stage(t + 1, buf ^ 1);

        bf16x8 wf[4];
#pragma unroll
        for (int n = 0; n < 4; ++n) {
            int r = wn * 64 + n * 16 + l15;
            int p = lk ^ ((l15 >> 1) & 3);
            wf[n] = *(const bf16x8*)&lBf[buf][r * 32 + p * 8];
        }
#pragma unroll
        for (int m = 0; m < 4; ++m) {
            int r  = wm * 64 + m * 16 + l15;
            int p0 = (2 * lk)     ^ (l15 & 7);
            int p1 = (2 * lk + 1) ^ (l15 & 7);
            float4 a0 = *(const float4*)&lAf[buf][r * 32 + p0 * 4];
            float4 a1 = *(const float4*)&lAf[buf][r * 32 + p1 * 4];
            bf16x8 xf;
            xf[0] = (__bf16)a0.x; xf[1] = (__bf16)a0.y;
            xf[2] = (__bf16)a0.z; xf[3] = (__bf16)a0.w;
            xf[4] = (__bf16)a1.x; xf[5] = (__bf16)a1.y;
            xf[6] = (__bf16)a1.z; xf[7] = (__bf16)a1.w;
#pragma unroll
            for (int n = 0; n < 4; ++n)
                acc[m][n] = __builtin_amdgcn_mfma_f32_16x16x32_bf16(
                    wf[n], xf, acc[m][n], 0, 0, 0);
        }
        __syncthreads();
    }

#pragma unroll
    for (int m = 0; m < 4; ++m) {
#pragma unroll
        for (int n = 0; n < 4; ++n) {
            const int colB = colb + wn * 64 + n * 16 + lk * 4;
            const float4 b4 = *(const float4*)(bias + colB);
            size_t off = (size_t)(row0 + wm * 64 + m * 16 + l15) * OUT_DIM + colB;
            const float4 u4 = *(const float4*)(du + off);
            float4 o;
            o.x = (acc[m][n][0] + b4.x) * ((u4.x >= 0.2f) ? 1.25f : 0.0f);
            o.y = (acc[m][n][1] + b4.y) * ((u4.y >= 0.2f) ? 1.25f : 0.0f);
            o.z = (acc[m][n][2] + b4.z) * ((u4.z >= 0.2f) ? 1.25f : 0.0f);
            o.w = (acc[m][n][3] + b4.w) * ((u4.w >= 0.2f) ? 1.25f : 0.0f);
            *(float4*)(out + off) = o;
        }
    }
}

extern "C" void kernel_launch(void* const* d_in, const int* in_sizes, int n_in,
                              void* d_out, int out_size, void* d_ws, size_t ws_size,
                              hipStream_t stream) {
    const float* x    = (const float*)d_in[0];
    const float* wmu  = (const float*)d_in[1];
    const float* wrho = (const float*)d_in[2];
    const float* bmu  = (const float*)d_in[3];
    const float* brho = (const float*)d_in[4];
    const float* weps = (const float*)d_in[5];
    const float* beps = (const float*)d_in[6];
    const float* du   = (const float*)d_in[7];
    float* out = (float*)d_out;

    u16*   wbf  = (u16*)d_ws;
    float* bias = (float*)((char*)d_ws + OUT_DIM * IN_DIM * sizeof(u16));
    u16*   xb   = (u16*)((char*)d_ws + (1 << 20));   // x_bf16 at +1 MB

    const size_t need = (1u << 20) + (size_t)65536 * IN_DIM * sizeof(u16);

    prep_kernel<<<256, 256, 0, stream>>>(wmu, wrho, weps, bmu, brho, beps, wbf, bias);

    if (ws_size >= need) {
        cvt_kernel<<<4096, 256, 0, stream>>>(x, xb);
        // 256 M-bands x 2 N-bands, fat steps: 512 blocks x 1024 thr
        bayes_gemm_kernel<<<512, 1024, 0, stream>>>(xb, du, wbf, bias, out);
    } else {
        bayes_gemm_f32a<<<2048, 256, 0, stream>>>(x, du, wbf, bias, out);
    }
}